// Round 1
// baseline (1241.387 us; speedup 1.0000x reference)
//
#include <hip/hip_runtime.h>
#include <math.h>

// ---------------- degree / normalization ----------------

__global__ void k_init_deg(float* deg, int N) {
    int i = blockIdx.x * blockDim.x + threadIdx.x;
    if (i < N) deg[i] = 1.0f;
}

__global__ void k_count_deg(const int* __restrict__ dst, float* deg, int E) {
    int e = blockIdx.x * blockDim.x + threadIdx.x;
    if (e < E) atomicAdd(&deg[dst[e]], 1.0f);
}

__global__ void k_dis(float* deg, int N) {
    int i = blockIdx.x * blockDim.x + threadIdx.x;
    if (i < N) deg[i] = 1.0f / sqrtf(deg[i]);
}

__global__ void k_enorm(const int* __restrict__ src, const int* __restrict__ dst,
                        const float* __restrict__ dis, float* __restrict__ enorm, int E) {
    int e = blockIdx.x * blockDim.x + threadIdx.x;
    if (e < E) enorm[e] = dis[src[e]] * dis[dst[e]];
}

// ---------------- GEMM1: h1 = x @ W1  (no bias; bias added post-agg) ----------------
// M=20000, K=386, Nc=256. 64x64 tile, 256 threads, 4x4 micro-tile, BK=8.

#define BM 64
#define BN 64
#define BK 8

__global__ __launch_bounds__(256) void k_gemm1(
    const float* __restrict__ A, const float* __restrict__ B,
    float* __restrict__ C, int M, int K, int Nc) {
    __shared__ float As[BK][BM];   // transposed A tile: As[kk][m]
    __shared__ float Bs[BK][BN];
    const int bm = blockIdx.x * BM;
    const int bn = blockIdx.y * BN;
    const int tid = threadIdx.x;
    const int tm = (tid >> 4) << 2;   // (tid/16)*4
    const int tn = (tid & 15) << 2;   // (tid%16)*4
    float acc[4][4] = {};

    for (int k0 = 0; k0 < K; k0 += BK) {
        #pragma unroll
        for (int i = 0; i < 2; ++i) {           // 512 A elems / 256 threads
            int idx = tid + i * 256;
            int r = idx >> 3, kk = idx & 7;
            int row = bm + r, kg = k0 + kk;
            As[kk][r] = (row < M && kg < K) ? A[(long long)row * K + kg] : 0.0f;
        }
        #pragma unroll
        for (int i = 0; i < 2; ++i) {           // 512 B elems / 256 threads
            int idx = tid + i * 256;
            int kk = idx >> 6, c = idx & 63;
            int kg = k0 + kk;
            Bs[kk][c] = (kg < K) ? B[(long long)kg * Nc + bn + c] : 0.0f;
        }
        __syncthreads();
        #pragma unroll
        for (int kk = 0; kk < BK; ++kk) {
            float4 a = *(const float4*)&As[kk][tm];
            float4 b = *(const float4*)&Bs[kk][tn];
            float av[4] = {a.x, a.y, a.z, a.w};
            float bv[4] = {b.x, b.y, b.z, b.w};
            #pragma unroll
            for (int i = 0; i < 4; ++i)
                #pragma unroll
                for (int j = 0; j < 4; ++j)
                    acc[i][j] = fmaf(av[i], bv[j], acc[i][j]);
        }
        __syncthreads();
    }

    #pragma unroll
    for (int i = 0; i < 4; ++i) {
        int row = bm + tm + i;
        if (row < M) {
            float4 v = make_float4(acc[i][0], acc[i][1], acc[i][2], acc[i][3]);
            *(float4*)&C[(long long)row * Nc + bn + tn] = v;
        }
    }
}

// ---------------- layer-1 aggregation ----------------

// agg = h1 * self_norm   (self_norm = dis^2); fully initializes agg
__global__ void k_self1(const float* __restrict__ h1, const float* __restrict__ dis,
                        float* __restrict__ agg, int N, int H4) {
    int idx = blockIdx.x * blockDim.x + threadIdx.x;   // over N*H/4
    int total = N * H4;
    if (idx >= total) return;
    int n = idx / H4;
    float s = dis[n];
    s = s * s;
    float4 v = ((const float4*)h1)[idx];
    v.x *= s; v.y *= s; v.z *= s; v.w *= s;
    ((float4*)agg)[idx] = v;
}

// one wave per edge; lane handles 4 features (H==256)
__global__ __launch_bounds__(256) void k_scatter1(
    const float* __restrict__ h1, const int* __restrict__ src,
    const int* __restrict__ dst, const float* __restrict__ enorm,
    float* __restrict__ agg, int E, int H) {
    int e = blockIdx.x * 4 + (threadIdx.x >> 6);
    if (e >= E) return;
    int lane = threadIdx.x & 63;
    int s = src[e], d = dst[e];
    float w = enorm[e];
    float4 v = ((const float4*)(h1 + (long long)s * H))[lane];
    float* ap = agg + (long long)d * H + lane * 4;
    atomicAdd(ap + 0, v.x * w);
    atomicAdd(ap + 1, v.y * w);
    atomicAdd(ap + 2, v.z * w);
    atomicAdd(ap + 3, v.w * w);
}

__global__ void k_bias_relu(float* __restrict__ agg, const float* __restrict__ b,
                            int total, int H) {
    int idx = blockIdx.x * blockDim.x + threadIdx.x;
    if (idx >= total) return;
    int c = idx & (H - 1);   // H == 256 (power of 2)
    float v = agg[idx] + b[c];
    agg[idx] = v > 0.0f ? v : 0.0f;
}

// ---------------- layer 2 ----------------

// z[n][0:2] = h[n][:] @ W2 ; wave per node, H==256, OUT==2
__global__ __launch_bounds__(256) void k_gemm2(
    const float* __restrict__ h, const float* __restrict__ W2,
    float* __restrict__ z, int N, int H) {
    int n = blockIdx.x * 4 + (threadIdx.x >> 6);
    if (n >= N) return;
    int lane = threadIdx.x & 63;
    float4 v = ((const float4*)(h + (long long)n * H))[lane];
    const float4* w = (const float4*)W2 + lane * 2;  // W2[4l..4l+3][0:2]
    float4 w0 = w[0], w1 = w[1];
    float a0 = v.x * w0.x + v.y * w0.z + v.z * w1.x + v.w * w1.z;
    float a1 = v.x * w0.y + v.y * w0.w + v.z * w1.y + v.w * w1.w;
    #pragma unroll
    for (int off = 32; off > 0; off >>= 1) {
        a0 += __shfl_down(a0, off);
        a1 += __shfl_down(a1, off);
    }
    if (lane == 0) {
        z[n * 2 + 0] = a0;
        z[n * 2 + 1] = a1;
    }
}

__global__ void k_self2(const float* __restrict__ z, const float* __restrict__ dis,
                        float* __restrict__ agg2, int N) {
    int n = blockIdx.x * blockDim.x + threadIdx.x;
    if (n >= N) return;
    float s = dis[n];
    s = s * s;
    agg2[n * 2 + 0] = z[n * 2 + 0] * s;
    agg2[n * 2 + 1] = z[n * 2 + 1] * s;
}

__global__ void k_scatter2(const float* __restrict__ z, const int* __restrict__ src,
                           const int* __restrict__ dst, const float* __restrict__ enorm,
                           float* __restrict__ agg2, int E) {
    int e = blockIdx.x * blockDim.x + threadIdx.x;
    if (e >= E) return;
    int s = src[e], d = dst[e];
    float w = enorm[e];
    atomicAdd(&agg2[d * 2 + 0], z[s * 2 + 0] * w);
    atomicAdd(&agg2[d * 2 + 1], z[s * 2 + 1] * w);
}

__global__ void k_final(const float* __restrict__ agg2, const float* __restrict__ b2,
                        float* __restrict__ out, int total) {
    int i = blockIdx.x * blockDim.x + threadIdx.x;
    if (i >= total) return;
    out[i] = tanhf(agg2[i] + b2[i & 1]);
}

// ---------------- launch ----------------

extern "C" void kernel_launch(void* const* d_in, const int* in_sizes, int n_in,
                              void* d_out, int out_size, void* d_ws, size_t ws_size,
                              hipStream_t stream) {
    const float* x   = (const float*)d_in[0];
    const int*   src = (const int*)d_in[1];
    const int*   dst = (const int*)d_in[2];
    const float* W1  = (const float*)d_in[3];
    const float* b1  = (const float*)d_in[4];
    const float* W2  = (const float*)d_in[5];
    const float* b2  = (const float*)d_in[6];
    float* out = (float*)d_out;

    const int E   = in_sizes[1];
    const int H   = in_sizes[4];          // 256
    const int OUT = in_sizes[6];          // 2
    const int FIN = in_sizes[3] / H;      // 386
    const int N   = in_sizes[0] / FIN;    // 20000

    float* ws    = (float*)d_ws;
    float* dis   = ws;                       // N (deg then dis in place)
    float* enorm = dis + N;                  // E
    float* h1    = enorm + E;                // N*H
    float* agg1  = h1 + (size_t)N * H;       // N*H (becomes relu'd hidden)
    float* z2    = agg1 + (size_t)N * H;     // N*OUT
    float* agg2  = z2 + (size_t)N * OUT;     // N*OUT

    const int T = 256;

    k_init_deg<<<(N + T - 1) / T, T, 0, stream>>>(dis, N);
    k_count_deg<<<(E + T - 1) / T, T, 0, stream>>>(dst, dis, E);
    k_dis<<<(N + T - 1) / T, T, 0, stream>>>(dis, N);
    k_enorm<<<(E + T - 1) / T, T, 0, stream>>>(src, dst, dis, enorm, E);

    dim3 g1((N + BM - 1) / BM, H / BN);
    k_gemm1<<<g1, T, 0, stream>>>(x, W1, h1, N, FIN, H);

    int h4 = H >> 2;
    k_self1<<<(N * h4 + T - 1) / T, T, 0, stream>>>(h1, dis, agg1, N, h4);
    k_scatter1<<<(E + 3) / 4, T, 0, stream>>>(h1, src, dst, enorm, agg1, E, H);
    k_bias_relu<<<(N * H + T - 1) / T, T, 0, stream>>>(agg1, b1, N * H, H);

    k_gemm2<<<(N + 3) / 4, T, 0, stream>>>(agg1, W2, z2, N, H);
    k_self2<<<(N + T - 1) / T, T, 0, stream>>>(z2, dis, agg2, N);
    k_scatter2<<<(E + T - 1) / T, T, 0, stream>>>(z2, src, dst, enorm, agg2, E);
    k_final<<<(2 * N + T - 1) / T, T, 0, stream>>>(agg2, b2, out, 2 * N);
}

// Round 2
// 223.024 us; speedup vs baseline: 5.5662x; 5.5662x over previous
//
#include <hip/hip_runtime.h>
#include <math.h>

// ================= CSR build =================

__global__ void k_zero_int(int* p, int n) {
    int i = blockIdx.x * blockDim.x + threadIdx.x;
    if (i < n) p[i] = 0;
}

__global__ void k_count(const int* __restrict__ dst, int* __restrict__ counts, int E) {
    int e = blockIdx.x * blockDim.x + threadIdx.x;
    if (e < E) atomicAdd(&counts[dst[e]], 1);
}

// single-block exclusive scan over counts -> rowptr, plus dis = rsqrt(deg+1)
__global__ __launch_bounds__(1024) void k_scan(const int* __restrict__ cnt,
                                               int* __restrict__ rowptr,
                                               float* __restrict__ dis,
                                               int N, int E) {
    __shared__ int sdata[1024];
    const int tid = threadIdx.x;
    const int chunk = (N + 1023) / 1024;
    const int base = tid * chunk;
    int sum = 0;
    for (int i = 0; i < chunk; ++i) {
        int idx = base + i;
        if (idx < N) sum += cnt[idx];
    }
    sdata[tid] = sum;
    __syncthreads();
    for (int off = 1; off < 1024; off <<= 1) {
        int v = (tid >= off) ? sdata[tid - off] : 0;
        __syncthreads();
        sdata[tid] += v;
        __syncthreads();
    }
    int run = (tid == 0) ? 0 : sdata[tid - 1];
    for (int i = 0; i < chunk; ++i) {
        int idx = base + i;
        if (idx < N) {
            rowptr[idx] = run;
            dis[idx] = rsqrtf((float)(cnt[idx] + 1));
            run += cnt[idx];
        }
    }
    if (tid == 1023) rowptr[N] = E;
}

__global__ void k_fill(const int* __restrict__ src, const int* __restrict__ dst,
                       const int* __restrict__ rowptr, int* __restrict__ cursor,
                       const float* __restrict__ dis,
                       int* __restrict__ col, float* __restrict__ wgt, int E) {
    int e = blockIdx.x * blockDim.x + threadIdx.x;
    if (e >= E) return;
    int s = src[e], d = dst[e];
    int p = rowptr[d] + atomicAdd(&cursor[d], 1);
    col[p] = s;
    wgt[p] = dis[s] * dis[d];
}

// ================= GEMM1: h1 = x @ W1 =================
// M=20000, K=386, Nc=256. 64x64 tile, 256 threads, 4x4 micro-tile, BK=8.

#define BM 64
#define BN 64
#define BK 8

__global__ __launch_bounds__(256) void k_gemm1(
    const float* __restrict__ A, const float* __restrict__ B,
    float* __restrict__ C, int M, int K, int Nc) {
    __shared__ float As[BK][BM];
    __shared__ float Bs[BK][BN];
    const int bm = blockIdx.x * BM;
    const int bn = blockIdx.y * BN;
    const int tid = threadIdx.x;
    const int tm = (tid >> 4) << 2;
    const int tn = (tid & 15) << 2;
    float acc[4][4] = {};

    for (int k0 = 0; k0 < K; k0 += BK) {
        #pragma unroll
        for (int i = 0; i < 2; ++i) {
            int idx = tid + i * 256;
            int r = idx >> 3, kk = idx & 7;
            int row = bm + r, kg = k0 + kk;
            As[kk][r] = (row < M && kg < K) ? A[(long long)row * K + kg] : 0.0f;
        }
        #pragma unroll
        for (int i = 0; i < 2; ++i) {
            int idx = tid + i * 256;
            int kk = idx >> 6, c = idx & 63;
            int kg = k0 + kk;
            Bs[kk][c] = (kg < K) ? B[(long long)kg * Nc + bn + c] : 0.0f;
        }
        __syncthreads();
        #pragma unroll
        for (int kk = 0; kk < BK; ++kk) {
            float4 a = *(const float4*)&As[kk][tm];
            float4 b = *(const float4*)&Bs[kk][tn];
            float av[4] = {a.x, a.y, a.z, a.w};
            float bv[4] = {b.x, b.y, b.z, b.w};
            #pragma unroll
            for (int i = 0; i < 4; ++i)
                #pragma unroll
                for (int j = 0; j < 4; ++j)
                    acc[i][j] = fmaf(av[i], bv[j], acc[i][j]);
        }
        __syncthreads();
    }

    #pragma unroll
    for (int i = 0; i < 4; ++i) {
        int row = bm + tm + i;
        if (row < M) {
            float4 v = make_float4(acc[i][0], acc[i][1], acc[i][2], acc[i][3]);
            *(float4*)&C[(long long)row * Nc + bn + tn] = v;
        }
    }
}

// ================= layer-1 aggregation (CSR gather, fused) =================
// one wave per dst row; lane handles 4 features (H==256 == 64*4)
// h[d] = relu( dis[d]^2*h1[d] + sum_j wgt[j]*h1[col[j]] + b1 )

__global__ __launch_bounds__(256) void k_agg1(
    const float* __restrict__ h1, const int* __restrict__ rowptr,
    const int* __restrict__ col, const float* __restrict__ wgt,
    const float* __restrict__ dis, const float* __restrict__ b1,
    float* __restrict__ h, int N, int H) {
    int d = blockIdx.x * 4 + (threadIdx.x >> 6);
    if (d >= N) return;
    int lane = threadIdx.x & 63;

    float s = dis[d];
    s = s * s;
    float4 acc = ((const float4*)(h1 + (long long)d * H))[lane];
    acc.x *= s; acc.y *= s; acc.z *= s; acc.w *= s;

    int beg = rowptr[d], end = rowptr[d + 1];
    int j = beg;
    for (; j + 1 < end; j += 2) {
        int c0 = col[j], c1 = col[j + 1];
        float w0 = wgt[j], w1 = wgt[j + 1];
        float4 v0 = ((const float4*)(h1 + (long long)c0 * H))[lane];
        float4 v1 = ((const float4*)(h1 + (long long)c1 * H))[lane];
        acc.x += w0 * v0.x + w1 * v1.x;
        acc.y += w0 * v0.y + w1 * v1.y;
        acc.z += w0 * v0.z + w1 * v1.z;
        acc.w += w0 * v0.w + w1 * v1.w;
    }
    if (j < end) {
        int c0 = col[j];
        float w0 = wgt[j];
        float4 v0 = ((const float4*)(h1 + (long long)c0 * H))[lane];
        acc.x += w0 * v0.x;
        acc.y += w0 * v0.y;
        acc.z += w0 * v0.z;
        acc.w += w0 * v0.w;
    }

    float4 b = ((const float4*)b1)[lane];
    acc.x = fmaxf(acc.x + b.x, 0.0f);
    acc.y = fmaxf(acc.y + b.y, 0.0f);
    acc.z = fmaxf(acc.z + b.z, 0.0f);
    acc.w = fmaxf(acc.w + b.w, 0.0f);
    ((float4*)(h + (long long)d * H))[lane] = acc;
}

// ================= layer 2 =================

// z[n][0:2] = h[n][:] @ W2 ; wave per node
__global__ __launch_bounds__(256) void k_gemm2(
    const float* __restrict__ h, const float* __restrict__ W2,
    float* __restrict__ z, int N, int H) {
    int n = blockIdx.x * 4 + (threadIdx.x >> 6);
    if (n >= N) return;
    int lane = threadIdx.x & 63;
    float4 v = ((const float4*)(h + (long long)n * H))[lane];
    const float4* w = (const float4*)W2 + lane * 2;
    float4 w0 = w[0], w1 = w[1];
    float a0 = v.x * w0.x + v.y * w0.z + v.z * w1.x + v.w * w1.z;
    float a1 = v.x * w0.y + v.y * w0.w + v.z * w1.y + v.w * w1.w;
    #pragma unroll
    for (int off = 32; off > 0; off >>= 1) {
        a0 += __shfl_down(a0, off);
        a1 += __shfl_down(a1, off);
    }
    if (lane == 0) {
        z[n * 2 + 0] = a0;
        z[n * 2 + 1] = a1;
    }
}

// out[d] = tanh( dis[d]^2*z[d] + sum_j wgt[j]*z[col[j]] + b2 ), thread per node
__global__ void k_agg2(const float* __restrict__ z, const int* __restrict__ rowptr,
                       const int* __restrict__ col, const float* __restrict__ wgt,
                       const float* __restrict__ dis, const float* __restrict__ b2,
                       float* __restrict__ out, int N) {
    int d = blockIdx.x * blockDim.x + threadIdx.x;
    if (d >= N) return;
    float s = dis[d];
    s = s * s;
    float a0 = s * z[d * 2 + 0];
    float a1 = s * z[d * 2 + 1];
    int beg = rowptr[d], end = rowptr[d + 1];
    for (int j = beg; j < end; ++j) {
        int c = col[j];
        float w = wgt[j];
        a0 += w * z[c * 2 + 0];
        a1 += w * z[c * 2 + 1];
    }
    out[d * 2 + 0] = tanhf(a0 + b2[0]);
    out[d * 2 + 1] = tanhf(a1 + b2[1]);
}

// ================= launch =================

extern "C" void kernel_launch(void* const* d_in, const int* in_sizes, int n_in,
                              void* d_out, int out_size, void* d_ws, size_t ws_size,
                              hipStream_t stream) {
    const float* x   = (const float*)d_in[0];
    const int*   src = (const int*)d_in[1];
    const int*   dst = (const int*)d_in[2];
    const float* W1  = (const float*)d_in[3];
    const float* b1  = (const float*)d_in[4];
    const float* W2  = (const float*)d_in[5];
    const float* b2  = (const float*)d_in[6];
    float* out = (float*)d_out;

    const int E   = in_sizes[1];
    const int H   = in_sizes[4];          // 256
    const int FIN = in_sizes[3] / H;      // 386
    const int N   = in_sizes[0] / FIN;    // 20000

    float* ws     = (float*)d_ws;
    float* dis    = ws;                        // N
    float* h1     = dis + N;                   // N*H
    float* h      = h1 + (size_t)N * H;        // N*H
    float* z      = h + (size_t)N * H;         // 2N
    float* wgt    = z + 2 * (size_t)N;         // E
    int*   col    = (int*)(wgt + E);           // E
    int*   counts = col + E;                   // N
    int*   cursor = counts + N;                // N
    int*   rowptr = cursor + N;                // N+1

    const int T = 256;

    // CSR build (counts and cursor are contiguous -> one zeroing pass)
    k_zero_int<<<(2 * N + T - 1) / T, T, 0, stream>>>(counts, 2 * N);
    k_count<<<(E + T - 1) / T, T, 0, stream>>>(dst, counts, E);
    k_scan<<<1, 1024, 0, stream>>>(counts, rowptr, dis, N, E);
    k_fill<<<(E + T - 1) / T, T, 0, stream>>>(src, dst, rowptr, cursor, dis, col, wgt, E);

    // layer 1
    dim3 g1((N + BM - 1) / BM, H / BN);
    k_gemm1<<<g1, T, 0, stream>>>(x, W1, h1, N, FIN, H);
    k_agg1<<<(N + 3) / 4, T, 0, stream>>>(h1, rowptr, col, wgt, dis, b1, h, N, H);

    // layer 2
    k_gemm2<<<(N + 3) / 4, T, 0, stream>>>(h, W2, z, N, H);
    k_agg2<<<(N + T - 1) / T, T, 0, stream>>>(z, rowptr, col, wgt, dis, b2, out, N);
}

// Round 3
// 150.629 us; speedup vs baseline: 8.2413x; 1.4806x over previous
//
#include <hip/hip_runtime.h>
#include <math.h>

typedef _Float16 f16;
typedef _Float16 f16x2 __attribute__((ext_vector_type(2)));
typedef _Float16 f16x4 __attribute__((ext_vector_type(4)));
typedef _Float16 f16x8 __attribute__((ext_vector_type(8)));
typedef float f32x4 __attribute__((ext_vector_type(4)));

#define FIN 386
#define KP  416   // FIN padded to multiple of 32
#define HH  256

// ================= CSR build =================

__global__ void k_zero_int(int* p, int n) {
    int i = blockIdx.x * blockDim.x + threadIdx.x;
    if (i < n) p[i] = 0;
}

__global__ void k_count(const int* __restrict__ dst, int* __restrict__ counts, int E) {
    int e = blockIdx.x * blockDim.x + threadIdx.x;
    if (e < E) atomicAdd(&counts[dst[e]], 1);
}

// single-block exclusive scan over counts -> rowptr, plus dis = rsqrt(deg+1)
__global__ __launch_bounds__(1024) void k_scan(const int* __restrict__ cnt,
                                               int* __restrict__ rowptr,
                                               float* __restrict__ dis,
                                               int N, int E) {
    __shared__ int sdata[1024];
    const int tid = threadIdx.x;
    const int chunk = (N + 1023) / 1024;
    const int base = tid * chunk;
    int sum = 0;
    for (int i = 0; i < chunk; ++i) {
        int idx = base + i;
        if (idx < N) sum += cnt[idx];
    }
    sdata[tid] = sum;
    __syncthreads();
    for (int off = 1; off < 1024; off <<= 1) {
        int v = (tid >= off) ? sdata[tid - off] : 0;
        __syncthreads();
        sdata[tid] += v;
        __syncthreads();
    }
    int run = (tid == 0) ? 0 : sdata[tid - 1];
    for (int i = 0; i < chunk; ++i) {
        int idx = base + i;
        if (idx < N) {
            rowptr[idx] = run;
            dis[idx] = rsqrtf((float)(cnt[idx] + 1));
            run += cnt[idx];
        }
    }
    if (tid == 1023) rowptr[N] = E;
}

__global__ void k_fill(const int* __restrict__ src, const int* __restrict__ dst,
                       const int* __restrict__ rowptr, int* __restrict__ cursor,
                       const float* __restrict__ dis,
                       int* __restrict__ col, float* __restrict__ wgt, int E) {
    int e = blockIdx.x * blockDim.x + threadIdx.x;
    if (e >= E) return;
    int s = src[e], d = dst[e];
    int p = rowptr[d] + atomicAdd(&cursor[d], 1);
    col[p] = s;
    wgt[p] = dis[s] * dis[d];
}

// ================= f16 conversions =================

// x [N][386] f32 -> xh [N][416] f16 (zero-padded)
__global__ void k_cvt_x(const float* __restrict__ x, f16* __restrict__ xh, int N) {
    int idx = blockIdx.x * blockDim.x + threadIdx.x;
    int total = N * (KP / 2);
    if (idx >= total) return;
    int row = idx / (KP / 2);
    int k2 = (idx - row * (KP / 2)) * 2;
    float v0 = 0.f, v1 = 0.f;
    if (k2 < FIN) {                       // FIN even -> k2+1 also valid
        v0 = x[(size_t)row * FIN + k2];
        v1 = x[(size_t)row * FIN + k2 + 1];
    }
    f16x2 t;
    t[0] = (f16)v0;
    t[1] = (f16)v1;
    *(f16x2*)(xh + (size_t)idx * 2) = t;
}

// W1 [386][256] f32 -> wt [256][416] f16 transposed (zero-padded)
__global__ void k_cvt_w(const float* __restrict__ W1, f16* __restrict__ wt) {
    int idx = blockIdx.x * blockDim.x + threadIdx.x;
    if (idx >= HH * KP) return;
    int c = idx / KP, k = idx - c * KP;
    float v = (k < FIN) ? W1[(size_t)k * HH + c] : 0.f;
    wt[(size_t)c * KP + k] = (f16)v;
}

// ================= GEMM1 (f16 MFMA): h1h = xh @ W1 =================
// M=20000, K=416, N=256. Tile 64x128, 256 threads = 4 waves, wave = 32x64.

#define GBM 64
#define GBN 128
#define GBK 32
#define LDP 40   // LDS pitch in f16 (80 B): balanced bank quads

__global__ __launch_bounds__(256) void k_gemm1(
    const f16* __restrict__ A, const f16* __restrict__ Bt,
    f16* __restrict__ C, int M) {
    __shared__ f16 As[GBM * LDP];
    __shared__ f16 Bs[GBN * LDP];
    const int bm = blockIdx.x * GBM;
    const int bn = blockIdx.y * GBN;
    const int tid = threadIdx.x;
    const int w = tid >> 6, l = tid & 63;
    const int wr = (w & 1) * 32;   // wave row offset within tile
    const int wc = (w >> 1) * 64;  // wave col offset within tile
    const int lrow = l & 15, lslot = l >> 4;

    f32x4 acc[2][4] = {};

    const int ar = tid >> 2, ap = tid & 3;   // staging: row, 16B-part
    const bool arow_ok = (bm + ar) < M;
    const f16* agp  = A  + (size_t)(bm + ar) * KP + ap * 8;
    const f16* bgp0 = Bt + (size_t)(bn + ar) * KP + ap * 8;
    const f16* bgp1 = bgp0 + (size_t)64 * KP;

    for (int k0 = 0; k0 < KP; k0 += GBK) {
        f16x8 av = {};
        if (arow_ok) av = *(const f16x8*)(agp + k0);
        f16x8 bv0 = *(const f16x8*)(bgp0 + k0);
        f16x8 bv1 = *(const f16x8*)(bgp1 + k0);
        *(f16x8*)&As[ar * LDP + ap * 8] = av;
        *(f16x8*)&Bs[ar * LDP + ap * 8] = bv0;
        *(f16x8*)&Bs[(ar + 64) * LDP + ap * 8] = bv1;
        __syncthreads();

        f16x8 a0 = *(const f16x8*)&As[(wr + lrow) * LDP + lslot * 8];
        f16x8 a1 = *(const f16x8*)&As[(wr + 16 + lrow) * LDP + lslot * 8];
        #pragma unroll
        for (int ni = 0; ni < 4; ++ni) {
            f16x8 b = *(const f16x8*)&Bs[(wc + ni * 16 + lrow) * LDP + lslot * 8];
            acc[0][ni] = __builtin_amdgcn_mfma_f32_16x16x32_f16(a0, b, acc[0][ni], 0, 0, 0);
            acc[1][ni] = __builtin_amdgcn_mfma_f32_16x16x32_f16(a1, b, acc[1][ni], 0, 0, 0);
        }
        __syncthreads();
    }

    // C/D layout: col = lane&15, row = (lane>>4)*4 + reg   [m89-verified]
    #pragma unroll
    for (int mi = 0; mi < 2; ++mi) {
        #pragma unroll
        for (int r = 0; r < 4; ++r) {
            int row = bm + wr + mi * 16 + lslot * 4 + r;
            if (row < M) {
                #pragma unroll
                for (int ni = 0; ni < 4; ++ni) {
                    C[(size_t)row * HH + bn + wc + ni * 16 + lrow] = (f16)acc[mi][ni][r];
                }
            }
        }
    }
}

// ================= layer-1 aggregation (CSR gather, fused, f16 h1) =================
// one wave per dst row; lane handles 4 features
// h[d] = relu( dis[d]^2*h1[d] + sum_j wgt[j]*h1[col[j]] + b1 )

__global__ __launch_bounds__(256) void k_agg1(
    const f16* __restrict__ h1, const int* __restrict__ rowptr,
    const int* __restrict__ col, const float* __restrict__ wgt,
    const float* __restrict__ dis, const float* __restrict__ b1,
    float* __restrict__ h, int N) {
    int d = blockIdx.x * 4 + (threadIdx.x >> 6);
    if (d >= N) return;
    int lane = threadIdx.x & 63;

    float s = dis[d];
    s = s * s;
    f16x4 v = ((const f16x4*)(h1 + (size_t)d * HH))[lane];
    float a0 = s * (float)v[0], a1 = s * (float)v[1];
    float a2 = s * (float)v[2], a3 = s * (float)v[3];

    int beg = rowptr[d], end = rowptr[d + 1];
    int j = beg;
    for (; j + 1 < end; j += 2) {
        int c0 = col[j], c1 = col[j + 1];
        float w0 = wgt[j], w1 = wgt[j + 1];
        f16x4 v0 = ((const f16x4*)(h1 + (size_t)c0 * HH))[lane];
        f16x4 v1 = ((const f16x4*)(h1 + (size_t)c1 * HH))[lane];
        a0 += w0 * (float)v0[0] + w1 * (float)v1[0];
        a1 += w0 * (float)v0[1] + w1 * (float)v1[1];
        a2 += w0 * (float)v0[2] + w1 * (float)v1[2];
        a3 += w0 * (float)v0[3] + w1 * (float)v1[3];
    }
    if (j < end) {
        int c0 = col[j];
        float w0 = wgt[j];
        f16x4 v0 = ((const f16x4*)(h1 + (size_t)c0 * HH))[lane];
        a0 += w0 * (float)v0[0];
        a1 += w0 * (float)v0[1];
        a2 += w0 * (float)v0[2];
        a3 += w0 * (float)v0[3];
    }

    const float4 b = ((const float4*)b1)[lane];
    float4 r;
    r.x = fmaxf(a0 + b.x, 0.0f);
    r.y = fmaxf(a1 + b.y, 0.0f);
    r.z = fmaxf(a2 + b.z, 0.0f);
    r.w = fmaxf(a3 + b.w, 0.0f);
    ((float4*)(h + (size_t)d * HH))[lane] = r;
}

// ================= layer 2 =================

// z[n][0:2] = h[n][:] @ W2 ; wave per node
__global__ __launch_bounds__(256) void k_gemm2(
    const float* __restrict__ h, const float* __restrict__ W2,
    float* __restrict__ z, int N) {
    int n = blockIdx.x * 4 + (threadIdx.x >> 6);
    if (n >= N) return;
    int lane = threadIdx.x & 63;
    float4 v = ((const float4*)(h + (size_t)n * HH))[lane];
    const float4* w = (const float4*)W2 + lane * 2;
    float4 w0 = w[0], w1 = w[1];
    float a0 = v.x * w0.x + v.y * w0.z + v.z * w1.x + v.w * w1.z;
    float a1 = v.x * w0.y + v.y * w0.w + v.z * w1.y + v.w * w1.w;
    #pragma unroll
    for (int off = 32; off > 0; off >>= 1) {
        a0 += __shfl_down(a0, off);
        a1 += __shfl_down(a1, off);
    }
    if (lane == 0) {
        z[n * 2 + 0] = a0;
        z[n * 2 + 1] = a1;
    }
}

// out[d] = tanh( dis[d]^2*z[d] + sum_j wgt[j]*z[col[j]] + b2 ), thread per node
__global__ void k_agg2(const float* __restrict__ z, const int* __restrict__ rowptr,
                       const int* __restrict__ col, const float* __restrict__ wgt,
                       const float* __restrict__ dis, const float* __restrict__ b2,
                       float* __restrict__ out, int N) {
    int d = blockIdx.x * blockDim.x + threadIdx.x;
    if (d >= N) return;
    float s = dis[d];
    s = s * s;
    float a0 = s * z[d * 2 + 0];
    float a1 = s * z[d * 2 + 1];
    int beg = rowptr[d], end = rowptr[d + 1];
    for (int j = beg; j < end; ++j) {
        int c = col[j];
        float w = wgt[j];
        a0 += w * z[c * 2 + 0];
        a1 += w * z[c * 2 + 1];
    }
    out[d * 2 + 0] = tanhf(a0 + b2[0]);
    out[d * 2 + 1] = tanhf(a1 + b2[1]);
}

// ================= launch =================

extern "C" void kernel_launch(void* const* d_in, const int* in_sizes, int n_in,
                              void* d_out, int out_size, void* d_ws, size_t ws_size,
                              hipStream_t stream) {
    const float* x   = (const float*)d_in[0];
    const int*   src = (const int*)d_in[1];
    const int*   dst = (const int*)d_in[2];
    const float* W1  = (const float*)d_in[3];
    const float* b1  = (const float*)d_in[4];
    const float* W2  = (const float*)d_in[5];
    const float* b2  = (const float*)d_in[6];
    float* out = (float*)d_out;

    const int E = in_sizes[1];
    const int N = in_sizes[0] / FIN;   // 20000

    // workspace layout (xh aliases h: xh dead before h is written)
    char* base = (char*)d_ws;
    float* h    = (float*)base;                         // N*HH f32
    f16*   xh   = (f16*)base;                           // N*KP f16 (16.6MB < 20.5MB)
    size_t off  = (size_t)N * HH * sizeof(float);
    f16* wth    = (f16*)(base + off); off += (size_t)HH * KP * sizeof(f16);
    f16* h1h    = (f16*)(base + off); off += (size_t)N * HH * sizeof(f16);
    float* dis  = (float*)(base + off); off += (size_t)N * sizeof(float);
    float* z    = (float*)(base + off); off += 2 * (size_t)N * sizeof(float);
    float* wgt  = (float*)(base + off); off += (size_t)E * sizeof(float);
    int* col    = (int*)(base + off); off += (size_t)E * sizeof(int);
    int* counts = (int*)(base + off); off += (size_t)N * sizeof(int);
    int* cursor = (int*)(base + off); off += (size_t)N * sizeof(int);
    int* rowptr = (int*)(base + off);

    const int T = 256;

    // f16 conversions
    k_cvt_x<<<(N * (KP / 2) + T - 1) / T, T, 0, stream>>>(x, xh, N);
    k_cvt_w<<<(HH * KP + T - 1) / T, T, 0, stream>>>(W1, wth);

    // CSR build (counts and cursor contiguous -> one zeroing pass)
    k_zero_int<<<(2 * N + T - 1) / T, T, 0, stream>>>(counts, 2 * N);
    k_count<<<(E + T - 1) / T, T, 0, stream>>>(dst, counts, E);
    k_scan<<<1, 1024, 0, stream>>>(counts, rowptr, dis, N, E);
    k_fill<<<(E + T - 1) / T, T, 0, stream>>>(src, dst, rowptr, cursor, dis, col, wgt, E);

    // layer 1
    dim3 g1((N + GBM - 1) / GBM, HH / GBN);
    k_gemm1<<<g1, T, 0, stream>>>(xh, wth, h1h, N);
    k_agg1<<<(N + 3) / 4, T, 0, stream>>>(h1h, rowptr, col, wgt, dis, b1, h, N);

    // layer 2
    k_gemm2<<<(N + 3) / 4, T, 0, stream>>>(h, W2, z, N);
    k_agg2<<<(N + T - 1) / T, T, 0, stream>>>(z, rowptr, col, wgt, dis, b2, out, N);
}

// Round 4
// 105.921 us; speedup vs baseline: 11.7199x; 1.4221x over previous
//
#include <hip/hip_runtime.h>
#include <math.h>

typedef _Float16 f16;
typedef _Float16 f16x4 __attribute__((ext_vector_type(4)));
typedef _Float16 f16x8 __attribute__((ext_vector_type(8)));
typedef float f32x4 __attribute__((ext_vector_type(4)));

#define FIN 386
#define KP  416   // FIN padded to multiple of 32
#define HH  256

// ================= prep: count degrees + convert W1 (transposed, padded) =================

__global__ __launch_bounds__(256) void k_prep(
    const int* __restrict__ dst, int* __restrict__ counts, int E, int nbc,
    const float* __restrict__ W1, f16* __restrict__ wt) {
    if ((int)blockIdx.x < nbc) {
        int e = blockIdx.x * 256 + threadIdx.x;
        if (e < E) atomicAdd(&counts[dst[e]], 1);
    } else {
        int idx = ((int)blockIdx.x - nbc) * 256 + threadIdx.x;
        if (idx < HH * KP) {
            int c = idx / KP, k = idx - c * KP;
            wt[(size_t)c * KP + k] = (k < FIN) ? (f16)W1[(size_t)k * HH + c] : (f16)0.f;
        }
    }
}

// ================= alloc: rowptr via atomic allocation, dis = rsqrt(deg+1) =================

__global__ void k_alloc(const int* __restrict__ counts, int* __restrict__ rowptr,
                        float* __restrict__ dis, int* __restrict__ total, int N) {
    int d = blockIdx.x * blockDim.x + threadIdx.x;
    if (d >= N) return;
    int c = counts[d];
    rowptr[d] = atomicAdd(total, c);   // wave-aggregated by compiler
    dis[d] = rsqrtf((float)(c + 1));
}

// ================= mid: CSR fill (blocks >= nbg) + GEMM1 f16 MFMA (blocks < nbg) =================
// GEMM1: h1h[M][256] = f16( f32 x[M][386] @ W1 ), tile 64x128, 4 waves, wave=32x64

#define GBM 64
#define GBN 128
#define GBK 32
#define LDP 40   // LDS pitch in f16 (80 B)

__global__ __launch_bounds__(256) void k_mid(
    const float* __restrict__ A, const f16* __restrict__ Bt,
    f16* __restrict__ C, int M, int nbg,
    const int* __restrict__ src, const int* __restrict__ dst,
    const int* __restrict__ rowptr, int* __restrict__ cursor,
    const float* __restrict__ dis, int2* __restrict__ cw, int E) {
    __shared__ f16 As[GBM * LDP];
    __shared__ f16 Bs[GBN * LDP];

    if ((int)blockIdx.x >= nbg) {
        int e = ((int)blockIdx.x - nbg) * 256 + threadIdx.x;
        if (e < E) {
            int s = src[e], d = dst[e];
            int p = rowptr[d] + atomicAdd(&cursor[d], 1);
            cw[p] = make_int2(s, __float_as_int(dis[s] * dis[d]));
        }
        return;
    }

    const int gb = blockIdx.x;
    const int bm = (gb >> 1) * GBM;
    const int bn = (gb & 1) * GBN;
    const int tid = threadIdx.x;
    const int w = tid >> 6, l = tid & 63;
    const int wr = (w & 1) * 32;
    const int wc = (w >> 1) * 64;
    const int lrow = l & 15, lslot = l >> 4;

    f32x4 acc[2][4] = {};

    const int ar = tid >> 2, ap = tid & 3;
    const int arow = bm + ar;
    const bool arow_ok = arow < M;
    const float* agp = A + (size_t)arow * FIN;
    const f16* bgp0 = Bt + (size_t)(bn + ar) * KP + ap * 8;
    const f16* bgp1 = bgp0 + (size_t)64 * KP;

    for (int k0 = 0; k0 < KP; k0 += GBK) {
        const int kg = k0 + ap * 8;
        f16x8 av = {};
        if (arow_ok) {
            if (kg + 8 <= FIN) {          // fast path: 4x float2 (8B-aligned)
                float2 f0 = *(const float2*)(agp + kg);
                float2 f1 = *(const float2*)(agp + kg + 2);
                float2 f2 = *(const float2*)(agp + kg + 4);
                float2 f3 = *(const float2*)(agp + kg + 6);
                av[0] = (f16)f0.x; av[1] = (f16)f0.y;
                av[2] = (f16)f1.x; av[3] = (f16)f1.y;
                av[4] = (f16)f2.x; av[5] = (f16)f2.y;
                av[6] = (f16)f3.x; av[7] = (f16)f3.y;
            } else {
                #pragma unroll
                for (int j = 0; j < 8; ++j)
                    av[j] = (kg + j < FIN) ? (f16)agp[kg + j] : (f16)0.f;
            }
        }
        f16x8 bv0 = *(const f16x8*)(bgp0 + k0);
        f16x8 bv1 = *(const f16x8*)(bgp1 + k0);
        *(f16x8*)&As[ar * LDP + ap * 8] = av;
        *(f16x8*)&Bs[ar * LDP + ap * 8] = bv0;
        *(f16x8*)&Bs[(ar + 64) * LDP + ap * 8] = bv1;
        __syncthreads();

        f16x8 a0 = *(const f16x8*)&As[(wr + lrow) * LDP + lslot * 8];
        f16x8 a1 = *(const f16x8*)&As[(wr + 16 + lrow) * LDP + lslot * 8];
        #pragma unroll
        for (int ni = 0; ni < 4; ++ni) {
            f16x8 b = *(const f16x8*)&Bs[(wc + ni * 16 + lrow) * LDP + lslot * 8];
            acc[0][ni] = __builtin_amdgcn_mfma_f32_16x16x32_f16(a0, b, acc[0][ni], 0, 0, 0);
            acc[1][ni] = __builtin_amdgcn_mfma_f32_16x16x32_f16(a1, b, acc[1][ni], 0, 0, 0);
        }
        __syncthreads();
    }

    // C/D layout: col = lane&15, row = (lane>>4)*4 + reg
    #pragma unroll
    for (int mi = 0; mi < 2; ++mi) {
        #pragma unroll
        for (int r = 0; r < 4; ++r) {
            int row = bm + wr + mi * 16 + lslot * 4 + r;
            if (row < M) {
                #pragma unroll
                for (int ni = 0; ni < 4; ++ni)
                    C[(size_t)row * HH + bn + wc + ni * 16 + lrow] = (f16)acc[mi][ni][r];
            }
        }
    }
}

// ================= agg1 + gemm2 fused =================
// wave per dst row: h_row = relu(dis^2*h1[d] + sum wgt*h1[col] + b1) in regs,
// then z[d][0:2] = h_row @ W2 via per-lane partials + shuffle reduce.

__global__ __launch_bounds__(256) void k_agg1(
    const f16* __restrict__ h1, const int* __restrict__ rowptr,
    const int* __restrict__ counts, const int2* __restrict__ cw,
    const float* __restrict__ dis, const float* __restrict__ b1,
    const float* __restrict__ W2, float* __restrict__ z, int N) {
    int d = blockIdx.x * 4 + (threadIdx.x >> 6);
    if (d >= N) return;
    int lane = threadIdx.x & 63;

    float s = dis[d];
    s = s * s;
    f16x4 v = ((const f16x4*)(h1 + (size_t)d * HH))[lane];
    float a0 = s * (float)v[0], a1 = s * (float)v[1];
    float a2 = s * (float)v[2], a3 = s * (float)v[3];

    int beg = rowptr[d], end = beg + counts[d];
    int j = beg;
    for (; j + 1 < end; j += 2) {
        int2 p0 = cw[j], p1 = cw[j + 1];
        float w0 = __int_as_float(p0.y), w1 = __int_as_float(p1.y);
        f16x4 v0 = ((const f16x4*)(h1 + (size_t)p0.x * HH))[lane];
        f16x4 v1 = ((const f16x4*)(h1 + (size_t)p1.x * HH))[lane];
        a0 += w0 * (float)v0[0] + w1 * (float)v1[0];
        a1 += w0 * (float)v0[1] + w1 * (float)v1[1];
        a2 += w0 * (float)v0[2] + w1 * (float)v1[2];
        a3 += w0 * (float)v0[3] + w1 * (float)v1[3];
    }
    if (j < end) {
        int2 p0 = cw[j];
        float w0 = __int_as_float(p0.y);
        f16x4 v0 = ((const f16x4*)(h1 + (size_t)p0.x * HH))[lane];
        a0 += w0 * (float)v0[0];
        a1 += w0 * (float)v0[1];
        a2 += w0 * (float)v0[2];
        a3 += w0 * (float)v0[3];
    }

    const float4 b = ((const float4*)b1)[lane];
    a0 = fmaxf(a0 + b.x, 0.0f);
    a1 = fmaxf(a1 + b.y, 0.0f);
    a2 = fmaxf(a2 + b.z, 0.0f);
    a3 = fmaxf(a3 + b.w, 0.0f);

    // gemm2: W2 is [256][2]; float4 pair covers rows 4l..4l+3
    const float4* wp = (const float4*)W2 + lane * 2;
    float4 w0 = wp[0], w1 = wp[1];
    float p0 = a0 * w0.x + a1 * w0.z + a2 * w1.x + a3 * w1.z;
    float p1 = a0 * w0.y + a1 * w0.w + a2 * w1.y + a3 * w1.w;
    #pragma unroll
    for (int off = 32; off > 0; off >>= 1) {
        p0 += __shfl_down(p0, off);
        p1 += __shfl_down(p1, off);
    }
    if (lane == 0) {
        float2 r = make_float2(p0, p1);
        *(float2*)(z + 2 * (size_t)d) = r;
    }
}

// ================= agg2 + tanh =================

__global__ void k_agg2(const float* __restrict__ z, const int* __restrict__ rowptr,
                       const int* __restrict__ counts, const int2* __restrict__ cw,
                       const float* __restrict__ dis, const float* __restrict__ b2,
                       float* __restrict__ out, int N) {
    int d = blockIdx.x * blockDim.x + threadIdx.x;
    if (d >= N) return;
    float s = dis[d];
    s = s * s;
    float2 zz = *(const float2*)(z + 2 * (size_t)d);
    float a0 = s * zz.x;
    float a1 = s * zz.y;
    int beg = rowptr[d], end = beg + counts[d];
    for (int j = beg; j < end; ++j) {
        int2 p = cw[j];
        float w = __int_as_float(p.y);
        float2 zv = *(const float2*)(z + 2 * (size_t)p.x);
        a0 += w * zv.x;
        a1 += w * zv.y;
    }
    out[d * 2 + 0] = tanhf(a0 + b2[0]);
    out[d * 2 + 1] = tanhf(a1 + b2[1]);
}

// ================= launch =================

extern "C" void kernel_launch(void* const* d_in, const int* in_sizes, int n_in,
                              void* d_out, int out_size, void* d_ws, size_t ws_size,
                              hipStream_t stream) {
    const float* x   = (const float*)d_in[0];
    const int*   src = (const int*)d_in[1];
    const int*   dst = (const int*)d_in[2];
    const float* W1  = (const float*)d_in[3];
    const float* b1  = (const float*)d_in[4];
    const float* W2  = (const float*)d_in[5];
    const float* b2  = (const float*)d_in[6];
    float* out = (float*)d_out;

    const int E = in_sizes[1];
    const int N = in_sizes[0] / FIN;   // 20000

    // workspace layout (all offsets 16B-aligned)
    char* base = (char*)d_ws;
    size_t off = 0;
    f16* wth    = (f16*)(base + off); off += (size_t)HH * KP * sizeof(f16);
    f16* h1h    = (f16*)(base + off); off += (size_t)N * HH * sizeof(f16);
    int2* cw    = (int2*)(base + off); off += (size_t)E * sizeof(int2);
    float* dis  = (float*)(base + off); off += (size_t)N * sizeof(float);
    float* z    = (float*)(base + off); off += 2 * (size_t)N * sizeof(float);
    int* counts = (int*)(base + off); off += (size_t)N * sizeof(int);
    int* cursor = (int*)(base + off); off += (size_t)N * sizeof(int);
    int* total  = (int*)(base + off); off += 4 * sizeof(int);
    int* rowptr = (int*)(base + off);

    const int T = 256;
    const int nbc = (E + T - 1) / T;              // count blocks
    const int nbw = (HH * KP + T - 1) / T;        // cvt_w blocks
    const int nbg = ((N + GBM - 1) / GBM) * (HH / GBN);  // gemm blocks
    const int nbf = (E + T - 1) / T;              // fill blocks

    // zero counts, cursor, total (contiguous)
    hipMemsetAsync(counts, 0, (2 * (size_t)N + 4) * sizeof(int), stream);

    k_prep<<<nbc + nbw, T, 0, stream>>>(dst, counts, E, nbc, W1, wth);
    k_alloc<<<(N + T - 1) / T, T, 0, stream>>>(counts, rowptr, dis, total, N);
    k_mid<<<nbg + nbf, T, 0, stream>>>(x, wth, h1h, N, nbg,
                                       src, dst, rowptr, cursor, dis, cw, E);
    k_agg1<<<(N + 3) / 4, T, 0, stream>>>(h1h, rowptr, counts, cw, dis, b1, W2, z, N);
    k_agg2<<<(N + T - 1) / T, T, 0, stream>>>(z, rowptr, counts, cw, dis, b2, out, N);
}